// Round 2
// baseline (469.638 us; speedup 1.0000x reference)
//
#include <hip/hip_runtime.h>

// Problem constants
#define E_TOT 100000
#define BLOCK 256

// fp16 MFMA fragment types (16x16x32: A/B = 8 halves = 4 VGPRs, C/D = 4 fp32)
typedef _Float16 half8  __attribute__((ext_vector_type(8)));
typedef _Float16 half4v __attribute__((ext_vector_type(4)));
typedef float    float4v __attribute__((ext_vector_type(4)));

__device__ __forceinline__ float silu_f(float x) {
    return x / (1.0f + __expf(-x));
}

// LDS plan (fp16, k-major rows padded to K+8 for 16B-aligned, 2-way-max-conflict b128 frag reads):
//   s_u   : union buffer, 17408 halves (34816 B)
//           phase A: emb [64 rows][72]  at 0      (4608 halves)
//                    W0^T [128 n][72]   at 4608   (9216 halves)
//           phase B: W1^T [128 n][136]  at 0      (17408 halves)
//           phase C: Pm^T [64 u][136]   at 0      (8704 halves)
//   s_h0  : [64 rows][136] halves (8704)
//   s_h1  : [64 rows][136] halves (8704)
// total 69632 B -> 2 blocks/CU (139 KB of 160 KB LDS)

__global__ __launch_bounds__(BLOCK, 2)
void tpmlp_mfma(const float* __restrict__ emb,
                const float* __restrict__ x1,
                const float* __restrict__ x2,
                const float* __restrict__ W0,
                const float* __restrict__ W1,
                const float* __restrict__ P1,
                const float* __restrict__ P2,
                const float* __restrict__ P3,
                const float* __restrict__ P4,
                const float* __restrict__ P5,
                float* __restrict__ out)
{
    const float INV_SQRT_EMB = 0.125f;               // 1/sqrt(64)
    const float INV_SQRT_H   = 0.08838834764831845f; // 1/sqrt(128)
    const float INV_SQRT3    = 0.5773502691896258f;
    const float INV_SQRT6    = 0.4082482904638631f;
    const float INV_SQRT2_C  = 0.7071067811865476f;

    __shared__ _Float16 s_u[17408];
    __shared__ _Float16 s_h0[64 * 136];
    __shared__ _Float16 s_h1[64 * 136];

    const int tid  = threadIdx.x;
    const int lane = tid & 63;
    const int wv   = tid >> 6;      // wave id == M-tile (16 rows each)
    const int l15  = lane & 15;
    const int lq   = lane >> 4;     // quad 0..3
    const int e0   = blockIdx.x * 64;

    // ---- Stage emb (fp32->fp16, [row][72]) and W0^T ([n][72]) ----
    #pragma unroll
    for (int i = 0; i < 4; ++i) {
        int idx4 = tid + i * 256;          // 1024 float4s = 64x64 floats
        int row  = idx4 >> 4;
        int c4   = (idx4 & 15) << 2;
        float4v v = {0.f, 0.f, 0.f, 0.f};
        if (e0 + row < E_TOT)
            v = *(const float4v*)(emb + (size_t)(e0 + row) * 64 + c4);
        half4v h;
        h[0] = (_Float16)v[0]; h[1] = (_Float16)v[1];
        h[2] = (_Float16)v[2]; h[3] = (_Float16)v[3];
        *(half4v*)&s_u[row * 72 + c4] = h;
    }
    // W0 is [k=64][n=128]; store transposed [n][k]. Strided global reads stay
    // in L1 (32 KB); LDS writes are lane-contiguous -> conflict-free.
    #pragma unroll 8
    for (int i = 0; i < 32; ++i) {
        int idx = tid + (i << 8);
        int k = idx & 63, n = idx >> 6;
        s_u[4608 + n * 72 + k] = (_Float16)W0[k * 128 + n];
    }
    __syncthreads();

    // ---- G1: h0 = silu(emb @ W0 / 8), M=64 N=128 K=64 ----
    {
        half8 a0 = *(const half8*)&s_u[(wv * 16 + l15) * 72 + lq * 8];
        half8 a1 = *(const half8*)&s_u[(wv * 16 + l15) * 72 + 32 + lq * 8];
        #pragma unroll
        for (int nt = 0; nt < 8; ++nt) {
            float4v c = {0.f, 0.f, 0.f, 0.f};
            half8 b0 = *(const half8*)&s_u[4608 + (nt * 16 + l15) * 72 + lq * 8];
            half8 b1 = *(const half8*)&s_u[4608 + (nt * 16 + l15) * 72 + 32 + lq * 8];
            c = __builtin_amdgcn_mfma_f32_16x16x32_f16(a0, b0, c, 0, 0, 0);
            c = __builtin_amdgcn_mfma_f32_16x16x32_f16(a1, b1, c, 0, 0, 0);
            #pragma unroll
            for (int r = 0; r < 4; ++r) {
                float h = silu_f(c[r] * INV_SQRT_EMB);
                s_h0[(wv * 16 + lq * 4 + r) * 136 + nt * 16 + l15] = (_Float16)h;
            }
        }
    }
    __syncthreads();   // G1 reads of s_u done; s_h0 written

    // ---- Stage W1^T ([n=128][136]) ----
    #pragma unroll 8
    for (int i = 0; i < 64; ++i) {
        int idx = tid + (i << 8);
        int k = idx & 127, n = idx >> 7;
        s_u[n * 136 + k] = (_Float16)W1[k * 128 + n];
    }
    __syncthreads();

    // ---- G2: h1 = silu(h0 @ W1 / sqrt(128)), M=64 N=128 K=128 ----
    {
        half8 a2[4];
        #pragma unroll
        for (int kt = 0; kt < 4; ++kt)
            a2[kt] = *(const half8*)&s_h0[(wv * 16 + l15) * 136 + kt * 32 + lq * 8];
        #pragma unroll
        for (int nt = 0; nt < 8; ++nt) {
            float4v c = {0.f, 0.f, 0.f, 0.f};
            #pragma unroll
            for (int kt = 0; kt < 4; ++kt) {
                half8 b = *(const half8*)&s_u[(nt * 16 + l15) * 136 + kt * 32 + lq * 8];
                c = __builtin_amdgcn_mfma_f32_16x16x32_f16(a2[kt], b, c, 0, 0, 0);
            }
            #pragma unroll
            for (int r = 0; r < 4; ++r) {
                float h = silu_f(c[r] * INV_SQRT_H);
                s_h1[(wv * 16 + lq * 4 + r) * 136 + nt * 16 + l15] = (_Float16)h;
            }
        }
    }
    __syncthreads();   // G2 reads of s_u done; s_h1 written

    // ---- G3: w_m = h1 @ P_m, m=0..4, accumulated in fp32 C-frags ----
    half8 a3[4];
    #pragma unroll
    for (int kt = 0; kt < 4; ++kt)
        a3[kt] = *(const half8*)&s_h1[(wv * 16 + l15) * 136 + kt * 32 + lq * 8];

    float4v acc3[5][4];   // [m][nt], 4 fp32 each = 80 VGPRs
    #pragma unroll
    for (int m = 0; m < 5; ++m)
        #pragma unroll
        for (int nt = 0; nt < 4; ++nt)
            acc3[m][nt] = (float4v){0.f, 0.f, 0.f, 0.f};

    const float* __restrict__ Pms[5] = {P1, P2, P3, P4, P5};
    #pragma unroll
    for (int m = 0; m < 5; ++m) {
        const float* __restrict__ Pm = Pms[m];
        // stage Pm^T ([u=64][136])
        #pragma unroll 8
        for (int i = 0; i < 32; ++i) {
            int idx = tid + (i << 8);
            int k = idx & 127, u = idx >> 7;
            s_u[u * 136 + k] = (_Float16)Pm[k * 64 + u];
        }
        __syncthreads();
        #pragma unroll
        for (int nt = 0; nt < 4; ++nt) {
            #pragma unroll
            for (int kt = 0; kt < 4; ++kt) {
                half8 b = *(const half8*)&s_u[(nt * 16 + l15) * 136 + kt * 32 + lq * 8];
                acc3[m][nt] = __builtin_amdgcn_mfma_f32_16x16x32_f16(a3[kt], b, acc3[m][nt], 0, 0, 0);
            }
        }
        __syncthreads();   // before next m overwrites s_u
    }

    // ---- Epilogue: directly from C-frag layout (row = lq*4+r, col = l15) ----
    #pragma unroll
    for (int r = 0; r < 4; ++r) {
        int e = e0 + wv * 16 + lq * 4 + r;
        if (e < E_TOT) {
            const float* x1p = x1 + (size_t)e * 256;
            float4v x2v = *(const float4v*)(x2 + (size_t)e * 4);
            float x20 = x2v[0], b0 = x2v[1], b1 = x2v[2], b2 = x2v[3];
            float* op = out + (size_t)e * 448;
            #pragma unroll
            for (int nt = 0; nt < 4; ++nt) {
                int u = nt * 16 + l15;
                float w1 = acc3[0][nt][r] * INV_SQRT_H;
                float w2 = acc3[1][nt][r] * INV_SQRT_H;
                float w3 = acc3[2][nt][r] * INV_SQRT_H;
                float w4 = acc3[3][nt][r] * INV_SQRT_H;
                float w5 = acc3[4][nt][r] * INV_SQRT_H;

                float x10 = x1p[u];
                float a0 = x1p[64 + 3 * u];
                float a1 = x1p[65 + 3 * u];
                float a2 = x1p[66 + 3 * u];

                float dot = a0 * b0 + a1 * b1 + a2 * b2;

                op[u] = INV_SQRT2_C * (w1 * x10 * x20 + w4 * dot * INV_SQRT3);

                op[64 + 3 * u]  = INV_SQRT2_C * (w2 * a0 * x20 + w3 * x10 * b0);
                op[65 + 3 * u]  = INV_SQRT2_C * (w2 * a1 * x20 + w3 * x10 * b1);
                op[66 + 3 * u]  = INV_SQRT2_C * (w2 * a2 * x20 + w3 * x10 * b2);

                op[256 + 3 * u] = w5 * (a1 * b2 - a2 * b1) * INV_SQRT6;
                op[257 + 3 * u] = w5 * (a2 * b0 - a0 * b2) * INV_SQRT6;
                op[258 + 3 * u] = w5 * (a0 * b1 - a1 * b0) * INV_SQRT6;
            }
        }
    }
}

extern "C" void kernel_launch(void* const* d_in, const int* in_sizes, int n_in,
                              void* d_out, int out_size, void* d_ws, size_t ws_size,
                              hipStream_t stream) {
    const float* emb = (const float*)d_in[0];
    const float* x1  = (const float*)d_in[1];
    const float* x2  = (const float*)d_in[2];
    const float* W0  = (const float*)d_in[3];
    const float* W1  = (const float*)d_in[4];
    const float* P1  = (const float*)d_in[5];
    const float* P2  = (const float*)d_in[6];
    const float* P3  = (const float*)d_in[7];
    const float* P4  = (const float*)d_in[8];
    const float* P5  = (const float*)d_in[9];

    dim3 grid((E_TOT + 63) / 64);
    dim3 block(BLOCK);
    tpmlp_mfma<<<grid, block, 0, stream>>>(emb, x1, x2, W0, W1,
                                           P1, P2, P3, P4, P5,
                                           (float*)d_out);
}

// Round 3
// 323.080 us; speedup vs baseline: 1.4536x; 1.4536x over previous
//
#include <hip/hip_runtime.h>

#define E_TOT 100000

typedef _Float16 half8   __attribute__((ext_vector_type(8)));
typedef float    float4v __attribute__((ext_vector_type(4)));

__device__ __forceinline__ float silu_f(float x) {
    return x / (1.0f + __expf(-x));
}

// ---- prep kernel: fp32 weights -> fp16 "B-fragment-linear" layout in ws ----
// Fragment for lane L of a wave, tile (nt,kt): B[k = kt*32 + (L>>4)*8 + j][n = nt*16 + (L&15)], j=0..7
// stored contiguously at [ ... ][lane][j] so a wave's half8 loads are 1 KB coalesced.
//   W0f: [nt=8][kt=2][64][8]  -> halves     0 ..  8191   (W0 is 64x128)
//   W1f: [nt=8][kt=4][64][8]  -> halves  8192 .. 24575   (W1 is 128x128)
//   Pf : [m=5][nt=4][kt=4][64][8] ->    24576 .. 65535   (P is 128x64)
__global__ void prep_weights(const float* __restrict__ W0,
                             const float* __restrict__ W1,
                             const float* __restrict__ P1,
                             const float* __restrict__ P2,
                             const float* __restrict__ P3,
                             const float* __restrict__ P4,
                             const float* __restrict__ P5,
                             _Float16* __restrict__ wf)
{
    int gid  = blockIdx.x * 256 + threadIdx.x;   // 65536 total
    int j    = gid & 7;
    int lane = (gid >> 3) & 63;
    int krow = ((lane >> 4) << 3) + j;           // k offset within 32-block
    int ncol = lane & 15;
    float v;
    if (gid < 8192) {
        int kt = (gid >> 9) & 1, nt = gid >> 10;
        v = W0[(kt * 32 + krow) * 128 + nt * 16 + ncol];
    } else if (gid < 24576) {
        int rem = gid - 8192;
        int kt = (rem >> 9) & 3, nt = rem >> 11;
        v = W1[(kt * 32 + krow) * 128 + nt * 16 + ncol];
    } else {
        int rem = gid - 24576;
        int kt = (rem >> 9) & 3, nt = (rem >> 11) & 3, m = rem >> 13;
        const float* Pm = (m == 0) ? P1 : (m == 1) ? P2 : (m == 2) ? P3 : (m == 3) ? P4 : P5;
        v = Pm[(kt * 32 + krow) * 64 + nt * 16 + ncol];
    }
    wf[gid] = (_Float16)v;
}

// ---- main kernel: 64 rows/block, 4 waves (1 M-tile each), 17.4 KB LDS ----
__global__ __launch_bounds__(256, 4)
void tpmlp_main(const float* __restrict__ emb,
                const float* __restrict__ x1,
                const float* __restrict__ x2,
                const _Float16* __restrict__ wf,
                float* __restrict__ out)
{
    const float INV_SQRT_EMB = 0.125f;
    const float INV_SQRT_H   = 0.08838834764831845f;
    const float INV_SQRT3    = 0.5773502691896258f;
    const float INV_SQRT6    = 0.4082482904638631f;
    const float INV_SQRT2_C  = 0.7071067811865476f;

    __shared__ _Float16 s_h[64 * 136];   // h buffer, reused h0 -> h1 (17408 B)

    const int tid  = threadIdx.x;
    const int lane = tid & 63;
    const int wv   = tid >> 6;
    const int l15  = lane & 15;
    const int lq   = lane >> 4;
    const int e0   = blockIdx.x * 64;

    const _Float16* __restrict__ W0f = wf;
    const _Float16* __restrict__ W1f = wf + 8192;
    const _Float16* __restrict__ Pf  = wf + 24576;

    // ---- A1 fragments straight from emb (fp32 global -> fp16 regs) ----
    half8 a0 = {0,0,0,0,0,0,0,0}, a1 = {0,0,0,0,0,0,0,0};
    {
        int row = e0 + wv * 16 + l15;
        if (row < E_TOT) {
            const float* er = emb + (size_t)row * 64 + lq * 8;
            float4v v0 = *(const float4v*)er;
            float4v v1 = *(const float4v*)(er + 4);
            float4v v2 = *(const float4v*)(er + 32);
            float4v v3 = *(const float4v*)(er + 36);
            #pragma unroll
            for (int t = 0; t < 4; ++t) { a0[t] = (_Float16)v0[t]; a0[4+t] = (_Float16)v1[t]; }
            #pragma unroll
            for (int t = 0; t < 4; ++t) { a1[t] = (_Float16)v2[t]; a1[4+t] = (_Float16)v3[t]; }
        }
    }

    // ---- G1: h0 = silu(emb @ W0 / 8) ----
    #pragma unroll
    for (int nt = 0; nt < 8; ++nt) {
        float4v c = {0.f, 0.f, 0.f, 0.f};
        half8 b0 = *(const half8*)&W0f[((nt * 2 + 0) * 64 + lane) * 8];
        half8 b1 = *(const half8*)&W0f[((nt * 2 + 1) * 64 + lane) * 8];
        c = __builtin_amdgcn_mfma_f32_16x16x32_f16(a0, b0, c, 0, 0, 0);
        c = __builtin_amdgcn_mfma_f32_16x16x32_f16(a1, b1, c, 0, 0, 0);
        #pragma unroll
        for (int r = 0; r < 4; ++r)
            s_h[(wv * 16 + lq * 4 + r) * 136 + nt * 16 + l15] =
                (_Float16)silu_f(c[r] * INV_SQRT_EMB);
    }
    __syncthreads();

    // ---- A2 fragments from h0 ----
    half8 a2[4];
    #pragma unroll
    for (int kt = 0; kt < 4; ++kt)
        a2[kt] = *(const half8*)&s_h[(wv * 16 + l15) * 136 + kt * 32 + lq * 8];
    __syncthreads();   // all reads done before h1 overwrites

    // ---- G2: h1 = silu(h0 @ W1 / sqrt(128)) ----
    #pragma unroll
    for (int nt = 0; nt < 8; ++nt) {
        float4v c = {0.f, 0.f, 0.f, 0.f};
        #pragma unroll
        for (int kt = 0; kt < 4; ++kt) {
            half8 b = *(const half8*)&W1f[((nt * 4 + kt) * 64 + lane) * 8];
            c = __builtin_amdgcn_mfma_f32_16x16x32_f16(a2[kt], b, c, 0, 0, 0);
        }
        #pragma unroll
        for (int r = 0; r < 4; ++r)
            s_h[(wv * 16 + lq * 4 + r) * 136 + nt * 16 + l15] =
                (_Float16)silu_f(c[r] * INV_SQRT_H);
    }
    __syncthreads();

    // ---- A3 fragments from h1 (no further LDS writes) ----
    half8 a3[4];
    #pragma unroll
    for (int kt = 0; kt < 4; ++kt)
        a3[kt] = *(const half8*)&s_h[(wv * 16 + l15) * 136 + kt * 32 + lq * 8];

    // ---- G3: w_m = h1 @ P_m (5 matrices, fp32 C-frags, 80 VGPRs) ----
    float4v acc3[5][4];
    #pragma unroll
    for (int m = 0; m < 5; ++m)
        #pragma unroll
        for (int nt = 0; nt < 4; ++nt)
            acc3[m][nt] = (float4v){0.f, 0.f, 0.f, 0.f};

    #pragma unroll
    for (int m = 0; m < 5; ++m)
        #pragma unroll
        for (int nt = 0; nt < 4; ++nt)
            #pragma unroll
            for (int kt = 0; kt < 4; ++kt) {
                half8 b = *(const half8*)&Pf[((m * 16 + nt * 4 + kt) * 64 + lane) * 8];
                acc3[m][nt] = __builtin_amdgcn_mfma_f32_16x16x32_f16(a3[kt], b, acc3[m][nt], 0, 0, 0);
            }

    // ---- Epilogue: C-frag layout row = lq*4+r, col = l15 ----
    #pragma unroll
    for (int r = 0; r < 4; ++r) {
        int e = e0 + wv * 16 + lq * 4 + r;
        if (e < E_TOT) {
            const float* x1p = x1 + (size_t)e * 256;
            float4v x2v = *(const float4v*)(x2 + (size_t)e * 4);
            float x20 = x2v[0], b0 = x2v[1], b1 = x2v[2], b2 = x2v[3];
            float* op = out + (size_t)e * 448;
            #pragma unroll
            for (int nt = 0; nt < 4; ++nt) {
                int u = nt * 16 + l15;
                float w1 = acc3[0][nt][r] * INV_SQRT_H;
                float w2 = acc3[1][nt][r] * INV_SQRT_H;
                float w3 = acc3[2][nt][r] * INV_SQRT_H;
                float w4 = acc3[3][nt][r] * INV_SQRT_H;
                float w5 = acc3[4][nt][r] * INV_SQRT_H;

                float x10 = x1p[u];
                float a_0 = x1p[64 + 3 * u];
                float a_1 = x1p[65 + 3 * u];
                float a_2 = x1p[66 + 3 * u];

                float dot = a_0 * b0 + a_1 * b1 + a_2 * b2;

                op[u] = INV_SQRT2_C * (w1 * x10 * x20 + w4 * dot * INV_SQRT3);

                op[64 + 3 * u] = INV_SQRT2_C * (w2 * a_0 * x20 + w3 * x10 * b0);
                op[65 + 3 * u] = INV_SQRT2_C * (w2 * a_1 * x20 + w3 * x10 * b1);
                op[66 + 3 * u] = INV_SQRT2_C * (w2 * a_2 * x20 + w3 * x10 * b2);

                op[256 + 3 * u] = w5 * (a_1 * b2 - a_2 * b1) * INV_SQRT6;
                op[257 + 3 * u] = w5 * (a_2 * b0 - a_0 * b2) * INV_SQRT6;
                op[258 + 3 * u] = w5 * (a_0 * b1 - a_1 * b0) * INV_SQRT6;
            }
        }
    }
}

extern "C" void kernel_launch(void* const* d_in, const int* in_sizes, int n_in,
                              void* d_out, int out_size, void* d_ws, size_t ws_size,
                              hipStream_t stream) {
    const float* emb = (const float*)d_in[0];
    const float* x1  = (const float*)d_in[1];
    const float* x2  = (const float*)d_in[2];
    const float* W0  = (const float*)d_in[3];
    const float* W1  = (const float*)d_in[4];
    const float* P1  = (const float*)d_in[5];
    const float* P2  = (const float*)d_in[6];
    const float* P3  = (const float*)d_in[7];
    const float* P4  = (const float*)d_in[8];
    const float* P5  = (const float*)d_in[9];

    _Float16* wf = (_Float16*)d_ws;   // needs 131072 bytes

    prep_weights<<<dim3(256), dim3(256), 0, stream>>>(W0, W1, P1, P2, P3, P4, P5, wf);
    tpmlp_main<<<dim3((E_TOT + 63) / 64), dim3(256), 0, stream>>>(
        emb, x1, x2, wf, (float*)d_out);
}